// Round 3
// baseline (6363.739 us; speedup 1.0000x reference)
//
#include <hip/hip_runtime.h>
#include <math.h>

#define PI_F 3.14159265358979323846f

__device__ __forceinline__ float lrelu_f(float x){ return x >= 0.f ? x : 0.05f*x; }

// ---------------------------------------------------------------------------
// Index map: xu flat index -> lat*W + lon  (pure-gather form of grid_sample)
// xu is the C-order reshape of (H_out, W_out, Kh, Kw):
//   flat = oh*(Wo*9) + ow*9 + kh*3 + kw
// ---------------------------------------------------------------------------
__global__ void k_idxmap(int* __restrict__ map, int H, int W, int Wo, int total)
{
    int i = blockIdx.x*blockDim.x + threadIdx.x;
    if (i >= total) return;
    int oh  = i / (Wo*9);
    int rem = i % (Wo*9);
    int ow  = rem / 9;
    int r2  = rem % 9;
    int kh  = r2/3, kw = r2%3;
    int ihc = min(oh*2, H-1);
    int lat = min(max(ihc + kh - 1, 0), H-1);
    float phi = ((float)lat + 0.5f)/(float)H * PI_F - 0.5f*PI_F;
    float ca  = fmaxf(fabsf(cosf(phi)), 1e-3f);
    float d   = fminf(0.8f/ca, 4.0f);
    float jw  = (float)((ow*2) % W);
    float lonf = rintf(jw + d*(float)(kw-1));   // np.round = half-to-even
    int lon = (int)lonf % W; if (lon < 0) lon += W;
    map[i] = lat*W + lon;
}

// ---------------------------------------------------------------------------
// Fold avg_pool3(conv3x3(.)) into an effective 5x5 stride-3 kernel:
//   W5[u][v] = (1/9) * sum_{p,q in [0,2], u-p in [0,2], v-q in [0,2]} w[p][q]
// Stored TRANSPOSED: w5t[(ci*25 + u*5+v)*CO + co] for coalesced lane loads.
// ---------------------------------------------------------------------------
__global__ void k_w5(const float* __restrict__ w3, float* __restrict__ w5t, int CO, int CI)
{
    int i = blockIdx.x*blockDim.x + threadIdx.x;
    if (i >= CO*CI*25) return;
    int v = i % 5, u = (i/5) % 5;
    int cc = i / 25;                 // cc = co*CI + ci (OIHW order)
    int ci = cc % CI, co = cc / CI;
    const float* w = w3 + cc*9;
    int p0 = max(0, u-2), p1 = min(2, u);
    int q0 = max(0, v-2), q1 = min(2, v);
    float s = 0.f;
    for (int p=p0;p<=p1;++p)
        for (int q=q0;q<=q1;++q) s += w[p*3+q];
    w5t[(ci*25 + u*5 + v)*CO + co] = s*(1.0f/9.0f);
}

// transpose OIHW -> [ci*KH*KW][CO] for coalesced weight loads
__global__ void k_wT(const float* __restrict__ w, float* __restrict__ wt, int CO, int CIK)
{
    int i = blockIdx.x*blockDim.x + threadIdx.x;
    if (i >= CO*CIK) return;
    int co = i / CIK, j = i % CIK;
    wt[j*CO + co] = w[i];
}

// ---------------------------------------------------------------------------
// Fused sphere-conv: gather -> 5x5 stride-3 conv -> BN -> lrelu
// One block per (b, oh). Gathered slab (5 rows of xu, all cols) in LDS.
// Thread = (co-pair, ow-quad); weights in registers, rows via float4 LDS.
// ---------------------------------------------------------------------------
template<int CI,int CO,int OH,int OW,int RW,int IPLANE>
__global__ __launch_bounds__(256) void k_sconv(
    const float* __restrict__ in, const int* __restrict__ map,
    const float* __restrict__ w5t,
    const float* __restrict__ bg, const float* __restrict__ bb,
    const float* __restrict__ bm, const float* __restrict__ bv,
    float* __restrict__ out)
{
    constexpr int NCP = CO/2;
    constexpr int NQ  = (OW+3)/4;
    static_assert(NCP*NQ == 256, "thread mapping must cover block exactly");
    __shared__ __align__(16) float sx[CI*5*RW + 16];

    int b  = blockIdx.x / OH;
    int oh = blockIdx.x % OH;
    int tid = threadIdx.x;
    const float* xb = in + (size_t)b*CI*IPLANE;
    int r0 = oh*3;
    for (int i = tid; i < CI*5*RW; i += 256){
        int c  = i % RW;
        int t  = i / RW;
        int rr = t % 5;
        int ci = t / 5;
        int m  = map[(r0+rr)*RW + c];
        sx[(ci*5+rr)*RW + c] = xb[(size_t)ci*IPLANE + m];
    }
    __syncthreads();

    int cp  = tid % NCP;
    int q   = tid / NCP;
    int co0 = cp*2;
    int ow0 = q*4;
    float acc[2][4] = {{0.f,0.f,0.f,0.f},{0.f,0.f,0.f,0.f}};
    for (int ci=0; ci<CI; ++ci){
        float wa[25], wb2[25];
        #pragma unroll
        for (int j=0;j<25;++j){
            float2 w2 = *reinterpret_cast<const float2*>(w5t + (ci*25+j)*CO + co0);
            wa[j] = w2.x; wb2[j] = w2.y;
        }
        #pragma unroll
        for (int u=0;u<5;++u){
            const float* row = &sx[(ci*5+u)*RW + ow0*3];
            float4 a0 = *reinterpret_cast<const float4*>(row);
            float4 a1 = *reinterpret_cast<const float4*>(row+4);
            float4 a2 = *reinterpret_cast<const float4*>(row+8);
            float4 a3 = *reinterpret_cast<const float4*>(row+12);
            float rv[16] = {a0.x,a0.y,a0.z,a0.w, a1.x,a1.y,a1.z,a1.w,
                            a2.x,a2.y,a2.z,a2.w, a3.x,a3.y,a3.z,a3.w};
            #pragma unroll
            for (int k=0;k<4;++k){
                #pragma unroll
                for (int vi=0; vi<5; ++vi){
                    float s = rv[k*3+vi];
                    acc[0][k] = fmaf(s, wa[u*5+vi],  acc[0][k]);
                    acc[1][k] = fmaf(s, wb2[u*5+vi], acc[1][k]);
                }
            }
        }
    }
    #pragma unroll
    for (int j=0;j<2;++j){
        int co = co0 + j;
        float inv = bg[co]*rsqrtf(bv[co] + 1e-5f);
        float sh  = bb[co] - bm[co]*inv;
        #pragma unroll
        for (int k=0;k<4;++k){
            int ow = ow0 + k;
            if (ow < OW)
                out[((size_t)b*CO + co)*(OH*OW) + oh*OW + ow] = lrelu_f(fmaf(acc[j][k], inv, sh));
        }
    }
}

// ---------------------------------------------------------------------------
// Direct VALID conv + BN + lrelu. One block per batch item; whole input
// plane staged in LDS (row-padded to IWP for aligned float4 reads).
// ---------------------------------------------------------------------------
template<int CI,int CO,int KH,int KW,int S,int IH,int IW,int IWP,int OH,int OW>
__global__ __launch_bounds__(256) void k_conv(
    const float* __restrict__ in, const float* __restrict__ wt,
    const float* __restrict__ bg, const float* __restrict__ bb,
    const float* __restrict__ bm, const float* __restrict__ bv,
    float* __restrict__ out)
{
    __shared__ __align__(16) float sx[CI*IH*IWP + 16];
    int b = blockIdx.x, tid = threadIdx.x;
    const float* ib = in + (size_t)b*CI*IH*IW;
    for (int i = tid; i < CI*IH*IW; i += 256){
        int c = i % IW;
        int t = i / IW;
        sx[t*IWP + c] = ib[i];
    }
    __syncthreads();
    constexpr int OWT = (OW+3)/4;
    constexpr int NT  = (CO/2)*OH*OWT;
    for (int t = tid; t < NT; t += 256){
        int owt = t % OWT;
        int r   = t / OWT;
        int oh  = r % OH;
        int cp  = r / OH;
        int co0 = cp*2;
        int ow0 = owt*4;
        float acc[2][4] = {{0.f,0.f,0.f,0.f},{0.f,0.f,0.f,0.f}};
        for (int ci=0; ci<CI; ++ci){
            float wa[KH*KW], wb2[KH*KW];
            #pragma unroll
            for (int j=0;j<KH*KW;++j){
                float2 w2 = *reinterpret_cast<const float2*>(wt + (ci*KH*KW + j)*CO + co0);
                wa[j] = w2.x; wb2[j] = w2.y;
            }
            #pragma unroll
            for (int p=0;p<KH;++p){
                const float* row = &sx[(ci*IH + oh*S + p)*IWP + ow0*S];
                float4 x0 = *reinterpret_cast<const float4*>(row);
                float4 x1 = *reinterpret_cast<const float4*>(row+4);
                float rv[8] = {x0.x,x0.y,x0.z,x0.w,x1.x,x1.y,x1.z,x1.w};
                #pragma unroll
                for (int k=0;k<4;++k){
                    #pragma unroll
                    for (int qq=0; qq<KW; ++qq){
                        float s = rv[k*S+qq];
                        acc[0][k] = fmaf(s, wa[p*KW+qq],  acc[0][k]);
                        acc[1][k] = fmaf(s, wb2[p*KW+qq], acc[1][k]);
                    }
                }
            }
        }
        #pragma unroll
        for (int j=0;j<2;++j){
            int co = co0+j;
            float inv = bg[co]*rsqrtf(bv[co]+1e-5f);
            float sh  = bb[co] - bm[co]*inv;
            #pragma unroll
            for (int k=0;k<4;++k){
                int ow = ow0+k;
                if (ow < OW)
                    out[((size_t)b*CO+co)*(OH*OW) + oh*OW + ow] = lrelu_f(fmaf(acc[j][k], inv, sh));
            }
        }
    }
}

// ---------------------------------------------------------------------------
// fused = lrelu(h5_flat @ proj_w.T + v @ vproj_w.T + vproj_b)
// ---------------------------------------------------------------------------
__global__ __launch_bounds__(256) void k_head(
    const float* __restrict__ h5, const float* __restrict__ vin,
    const float* __restrict__ proj_w, const float* __restrict__ vproj_w,
    const float* __restrict__ vproj_b, float* __restrict__ fused)
{
    __shared__ __align__(16) float sh[2560];
    __shared__ float sv[9];
    int b = blockIdx.x, tid = threadIdx.x;
    for (int i = tid; i < 2560; i += 256) sh[i] = h5[(size_t)b*2560 + i];
    if (tid < 9) sv[tid] = vin[b*9 + tid];
    __syncthreads();
    const float* pw = proj_w + (size_t)tid*2560;
    float acc = 0.f;
    for (int k=0;k<2560;k+=4){
        float4 s4 = *reinterpret_cast<const float4*>(sh+k);
        float4 w4 = *reinterpret_cast<const float4*>(pw+k);
        acc = fmaf(s4.x,w4.x, fmaf(s4.y,w4.y, fmaf(s4.z,w4.z, fmaf(s4.w,w4.w, acc))));
    }
    float av = 0.f;
    #pragma unroll
    for (int k=0;k<9;++k) av += sv[k]*vproj_w[tid*9+k];
    fused[b*256+tid] = lrelu_f(acc + av + vproj_b[tid]);
}

// ---------------------------------------------------------------------------
// GRU cell: 6 dot-256 per (b, j)
// ---------------------------------------------------------------------------
__global__ __launch_bounds__(256) void k_gru(
    const float* __restrict__ fused, const float* __restrict__ hx,
    const float* __restrict__ wih, const float* __restrict__ whh,
    const float* __restrict__ bih, const float* __restrict__ bhh,
    float* __restrict__ hx_new)
{
    __shared__ __align__(16) float sf[256];
    __shared__ __align__(16) float shx[256];
    int b = blockIdx.x, j = threadIdx.x;
    sf[j]  = fused[b*256+j];
    shx[j] = hx[b*256+j];
    __syncthreads();
    float ga[3], gb[3];
    #pragma unroll
    for (int gi=0; gi<3; ++gi){
        const float* wi = wih + ((size_t)gi*256 + j)*256;
        const float* wh = whh + ((size_t)gi*256 + j)*256;
        float a = 0.f, c = 0.f;
        for (int k=0;k<256;k+=4){
            float4 f4  = *reinterpret_cast<const float4*>(sf+k);
            float4 h4  = *reinterpret_cast<const float4*>(shx+k);
            float4 wi4 = *reinterpret_cast<const float4*>(wi+k);
            float4 wh4 = *reinterpret_cast<const float4*>(wh+k);
            a = fmaf(f4.x,wi4.x, fmaf(f4.y,wi4.y, fmaf(f4.z,wi4.z, fmaf(f4.w,wi4.w, a))));
            c = fmaf(h4.x,wh4.x, fmaf(h4.y,wh4.y, fmaf(h4.z,wh4.z, fmaf(h4.w,wh4.w, c))));
        }
        ga[gi] = a + bih[gi*256+j];
        gb[gi] = c + bhh[gi*256+j];
    }
    float r = 1.f/(1.f+expf(-(ga[0]+gb[0])));
    float z = 1.f/(1.f+expf(-(ga[1]+gb[1])));
    float n = tanhf(ga[2] + r*gb[2]);
    hx_new[b*256+j] = (1.f-z)*n + z*shx[j];
}

// act = lrelu(hx_new) @ fc_w.T  -> (256,4)
__global__ void k_act(const float* __restrict__ hx_new, const float* __restrict__ fc_w,
                      float* __restrict__ act)
{
    int t = blockIdx.x*blockDim.x + threadIdx.x;
    if (t >= 1024) return;
    int b = t >> 2, o = t & 3;
    const float* h = hx_new + b*256;
    const float* w = fc_w + o*256;
    float acc = 0.f;
    for (int k=0;k<256;++k) acc = fmaf(lrelu_f(h[k]), w[k], acc);
    act[t] = acc;
}

extern "C" void kernel_launch(void* const* d_in, const int* in_sizes, int n_in,
                              void* d_out, int out_size, void* d_ws, size_t ws_size,
                              hipStream_t stream)
{
    const float* x      = (const float*)d_in[0];
    const float* vin    = (const float*)d_in[1];
    const float* hx     = (const float*)d_in[2];
    const float* sc0_w  = (const float*)d_in[3];
    const float* bn0g   = (const float*)d_in[4];
    const float* bn0b   = (const float*)d_in[5];
    const float* bn0m   = (const float*)d_in[6];
    const float* bn0v   = (const float*)d_in[7];
    const float* sc1_w  = (const float*)d_in[8];
    const float* bn1g   = (const float*)d_in[9];
    const float* bn1b   = (const float*)d_in[10];
    const float* bn1m   = (const float*)d_in[11];
    const float* bn1v   = (const float*)d_in[12];
    const float* c2_w   = (const float*)d_in[13];
    const float* bn2g   = (const float*)d_in[14];
    const float* bn2b   = (const float*)d_in[15];
    const float* bn2m   = (const float*)d_in[16];
    const float* bn2v   = (const float*)d_in[17];
    const float* c3_w   = (const float*)d_in[18];
    const float* bn3g   = (const float*)d_in[19];
    const float* bn3b   = (const float*)d_in[20];
    const float* bn3m   = (const float*)d_in[21];
    const float* bn3v   = (const float*)d_in[22];
    const float* c4_w   = (const float*)d_in[23];
    const float* bn4g   = (const float*)d_in[24];
    const float* bn4b   = (const float*)d_in[25];
    const float* bn4m   = (const float*)d_in[26];
    const float* bn4v   = (const float*)d_in[27];
    const float* c5_w   = (const float*)d_in[28];
    const float* bn5g   = (const float*)d_in[29];
    const float* bn5b   = (const float*)d_in[30];
    const float* bn5m   = (const float*)d_in[31];
    const float* bn5v   = (const float*)d_in[32];
    const float* proj_w = (const float*)d_in[33];
    const float* vproj_w= (const float*)d_in[34];
    const float* vproj_b= (const float*)d_in[35];
    const float* gru_wih= (const float*)d_in[36];
    const float* gru_whh= (const float*)d_in[37];
    const float* gru_bih= (const float*)d_in[38];
    const float* gru_bhh= (const float*)d_in[39];
    const float* fc_w   = (const float*)d_in[40];

    float* W = (float*)d_ws;
    size_t off = 0;
    int*   map0 = (int*)(W + off); off += 96*192;
    int*   map1 = (int*)(W + off); off += 48*96;
    float* w5t0 = W + off; off += 32*6*25;
    float* w5t1 = W + off; off += 64*32*25;
    float* wt2  = W + off; off += 64*64*9;
    float* wt3  = W + off; off += 64*64*4;
    float* wt4  = W + off; off += 128*64*9;
    float* wt5  = W + off; off += 128*128*9;
    float* bufA = W + off; off += (size_t)256*32*31*63;   // h0 / h2 / h4 / fused
    float* bufB = W + off; off += (size_t)256*64*15*31;   // h1 / h3 / h5

    // small precompute
    k_idxmap<<<72, 256, 0, stream>>>(map0, 64, 128, 64, 96*192);
    k_idxmap<<<18, 256, 0, stream>>>(map1, 31,  63, 32, 48*96);
    k_w5<<<(32*6*25 +255)/256, 256, 0, stream>>>(sc0_w, w5t0, 32, 6);
    k_w5<<<(64*32*25+255)/256, 256, 0, stream>>>(sc1_w, w5t1, 64, 32);
    k_wT<<<(64*64*9  +255)/256, 256, 0, stream>>>(c2_w, wt2, 64,  64*9);
    k_wT<<<(64*64*4  +255)/256, 256, 0, stream>>>(c3_w, wt3, 64,  64*4);
    k_wT<<<(128*64*9 +255)/256, 256, 0, stream>>>(c4_w, wt4, 128, 64*9);
    k_wT<<<(128*128*9+255)/256, 256, 0, stream>>>(c5_w, wt5, 128, 128*9);

    // backbone
    k_sconv<6,32,31,63,192,64*128><<<256*31, 256, 0, stream>>>(x,    map0, w5t0, bn0g,bn0b,bn0m,bn0v, bufA);
    k_sconv<32,64,15,31,96,31*63><<<256*15, 256, 0, stream>>>(bufA, map1, w5t1, bn1g,bn1b,bn1m,bn1v, bufB);
    k_conv<64,64,3,3,1,15,31,32,13,29><<<256,256,0,stream>>>(bufB, wt2, bn2g,bn2b,bn2m,bn2v, bufA);
    k_conv<64,64,2,2,2,13,29,32,6,14><<<256,256,0,stream>>>(bufA, wt3, bn3g,bn3b,bn3m,bn3v, bufB);
    k_conv<64,128,3,3,1,6,14,16,4,12><<<256,256,0,stream>>>(bufB, wt4, bn4g,bn4b,bn4m,bn4v, bufA);
    k_conv<128,128,3,3,1,4,12,12,2,10><<<256,256,0,stream>>>(bufA, wt5, bn5g,bn5b,bn5m,bn5v, bufB);

    // head
    k_head<<<256,256,0,stream>>>(bufB, vin, proj_w, vproj_w, vproj_b, bufA);
    float* outp = (float*)d_out;
    k_gru<<<256,256,0,stream>>>(bufA, hx, gru_wih, gru_whh, gru_bih, gru_bhh, outp + 1024);
    k_act<<<4,256,0,stream>>>(outp + 1024, fc_w, outp);
}

// Round 4
// 6225.119 us; speedup vs baseline: 1.0223x; 1.0223x over previous
//
#include <hip/hip_runtime.h>
#include <math.h>

#define PI_F 3.14159265358979323846f

__device__ __forceinline__ float lrelu_f(float x){ return x >= 0.f ? x : 0.05f*x; }

// ---------------------------------------------------------------------------
// Index map: xu flat index -> lat*W + lon  (pure-gather form of grid_sample)
// xu is the C-order reshape of (H_out, W_out, Kh, Kw):
//   flat = oh*(Wo*9) + ow*9 + kh*3 + kw
// ---------------------------------------------------------------------------
__global__ void k_idxmap(int* __restrict__ map, int H, int W, int Wo, int total)
{
    int i = blockIdx.x*blockDim.x + threadIdx.x;
    if (i >= total) return;
    int oh  = i / (Wo*9);
    int rem = i % (Wo*9);
    int ow  = rem / 9;
    int r2  = rem % 9;
    int kh  = r2/3, kw = r2%3;
    int ihc = min(oh*2, H-1);
    int lat = min(max(ihc + kh - 1, 0), H-1);
    float phi = ((float)lat + 0.5f)/(float)H * PI_F - 0.5f*PI_F;
    float ca  = fmaxf(fabsf(cosf(phi)), 1e-3f);
    float d   = fminf(0.8f/ca, 4.0f);
    float jw  = (float)((ow*2) % W);
    float lonf = rintf(jw + d*(float)(kw-1));   // np.round = half-to-even
    int lon = (int)lonf % W; if (lon < 0) lon += W;
    map[i] = lat*W + lon;
}

// ---------------------------------------------------------------------------
// Fold avg_pool3(conv3x3(.)) into an effective 5x5 stride-3 kernel:
//   W5[u][v] = (1/9) * sum_{p,q in [0,2], u-p in [0,2], v-q in [0,2]} w[p][q]
// Stored TRANSPOSED: w5t[(ci*25 + u*5+v)*CO + co] for coalesced lane loads.
// ---------------------------------------------------------------------------
__global__ void k_w5(const float* __restrict__ w3, float* __restrict__ w5t, int CO, int CI)
{
    int i = blockIdx.x*blockDim.x + threadIdx.x;
    if (i >= CO*CI*25) return;
    int v = i % 5, u = (i/5) % 5;
    int cc = i / 25;                 // cc = co*CI + ci (OIHW order)
    int ci = cc % CI, co = cc / CI;
    const float* w = w3 + cc*9;
    int p0 = max(0, u-2), p1 = min(2, u);
    int q0 = max(0, v-2), q1 = min(2, v);
    float s = 0.f;
    for (int p=p0;p<=p1;++p)
        for (int q=q0;q<=q1;++q) s += w[p*3+q];
    w5t[(ci*25 + u*5 + v)*CO + co] = s*(1.0f/9.0f);
}

// transpose OIHW -> [ci*KH*KW][CO] for coalesced weight loads
__global__ void k_wT(const float* __restrict__ w, float* __restrict__ wt, int CO, int CIK)
{
    int i = blockIdx.x*blockDim.x + threadIdx.x;
    if (i >= CO*CIK) return;
    int co = i / CIK, j = i % CIK;
    wt[j*CO + co] = w[i];
}

// ---------------------------------------------------------------------------
// Fused sphere-conv: gather -> 5x5 stride-3 conv -> BN -> lrelu
// One block per (b, oh). Gathered slab (5 rows of xu, all cols) in LDS.
// Thread = (co-pair, ow-quad); weights in registers, rows via float4 LDS.
// ---------------------------------------------------------------------------
template<int CI,int CO,int OH,int OW,int RW,int IPLANE>
__global__ __launch_bounds__(256) void k_sconv(
    const float* __restrict__ in, const int* __restrict__ map,
    const float* __restrict__ w5t,
    const float* __restrict__ bg, const float* __restrict__ bb,
    const float* __restrict__ bm, const float* __restrict__ bv,
    float* __restrict__ out)
{
    constexpr int NCP = CO/2;
    constexpr int NQ  = (OW+3)/4;
    static_assert(NCP*NQ == 256, "thread mapping must cover block exactly");
    __shared__ __align__(16) float sx[CI*5*RW + 16];

    int b  = blockIdx.x / OH;
    int oh = blockIdx.x % OH;
    int tid = threadIdx.x;
    const float* xb = in + (size_t)b*CI*IPLANE;
    int r0 = oh*3;
    for (int i = tid; i < CI*5*RW; i += 256){
        int c  = i % RW;
        int t  = i / RW;
        int rr = t % 5;
        int ci = t / 5;
        int m  = map[(r0+rr)*RW + c];
        sx[(ci*5+rr)*RW + c] = xb[(size_t)ci*IPLANE + m];
    }
    __syncthreads();

    int cp  = tid % NCP;
    int q   = tid / NCP;
    int co0 = cp*2;
    int ow0 = q*4;
    float acc[2][4] = {{0.f,0.f,0.f,0.f},{0.f,0.f,0.f,0.f}};
    for (int ci=0; ci<CI; ++ci){
        float wa[25], wb2[25];
        #pragma unroll
        for (int j=0;j<25;++j){
            float2 w2 = *reinterpret_cast<const float2*>(w5t + (ci*25+j)*CO + co0);
            wa[j] = w2.x; wb2[j] = w2.y;
        }
        #pragma unroll
        for (int u=0;u<5;++u){
            const float* row = &sx[(ci*5+u)*RW + ow0*3];
            float4 a0 = *reinterpret_cast<const float4*>(row);
            float4 a1 = *reinterpret_cast<const float4*>(row+4);
            float4 a2 = *reinterpret_cast<const float4*>(row+8);
            float4 a3 = *reinterpret_cast<const float4*>(row+12);
            float rv[16] = {a0.x,a0.y,a0.z,a0.w, a1.x,a1.y,a1.z,a1.w,
                            a2.x,a2.y,a2.z,a2.w, a3.x,a3.y,a3.z,a3.w};
            #pragma unroll
            for (int k=0;k<4;++k){
                #pragma unroll
                for (int vi=0; vi<5; ++vi){
                    float s = rv[k*3+vi];
                    acc[0][k] = fmaf(s, wa[u*5+vi],  acc[0][k]);
                    acc[1][k] = fmaf(s, wb2[u*5+vi], acc[1][k]);
                }
            }
        }
    }
    #pragma unroll
    for (int j=0;j<2;++j){
        int co = co0 + j;
        float inv = bg[co]*rsqrtf(bv[co] + 1e-5f);
        float sh  = bb[co] - bm[co]*inv;
        #pragma unroll
        for (int k=0;k<4;++k){
            int ow = ow0 + k;
            if (ow < OW)
                out[((size_t)b*CO + co)*(OH*OW) + oh*OW + ow] = lrelu_f(fmaf(acc[j][k], inv, sh));
        }
    }
}

// ---------------------------------------------------------------------------
// Direct VALID conv + BN + lrelu. One block per batch item; whole input
// plane staged in LDS (row-padded to IWP for aligned float4 reads).
// ---------------------------------------------------------------------------
template<int CI,int CO,int KH,int KW,int S,int IH,int IW,int IWP,int OH,int OW>
__global__ __launch_bounds__(256) void k_conv(
    const float* __restrict__ in, const float* __restrict__ wt,
    const float* __restrict__ bg, const float* __restrict__ bb,
    const float* __restrict__ bm, const float* __restrict__ bv,
    float* __restrict__ out)
{
    __shared__ __align__(16) float sx[CI*IH*IWP + 16];
    int b = blockIdx.x, tid = threadIdx.x;
    const float* ib = in + (size_t)b*CI*IH*IW;
    for (int i = tid; i < CI*IH*IW; i += 256){
        int c = i % IW;
        int t = i / IW;
        sx[t*IWP + c] = ib[i];
    }
    __syncthreads();
    constexpr int OWT = (OW+3)/4;
    constexpr int NT  = (CO/2)*OH*OWT;
    for (int t = tid; t < NT; t += 256){
        int owt = t % OWT;
        int r   = t / OWT;
        int oh  = r % OH;
        int cp  = r / OH;
        int co0 = cp*2;
        int ow0 = owt*4;
        float acc[2][4] = {{0.f,0.f,0.f,0.f},{0.f,0.f,0.f,0.f}};
        for (int ci=0; ci<CI; ++ci){
            float wa[KH*KW], wb2[KH*KW];
            #pragma unroll
            for (int j=0;j<KH*KW;++j){
                float2 w2 = *reinterpret_cast<const float2*>(wt + (ci*KH*KW + j)*CO + co0);
                wa[j] = w2.x; wb2[j] = w2.y;
            }
            #pragma unroll
            for (int p=0;p<KH;++p){
                const float* row = &sx[(ci*IH + oh*S + p)*IWP + ow0*S];
                float4 x0 = *reinterpret_cast<const float4*>(row);
                float4 x1 = *reinterpret_cast<const float4*>(row+4);
                float rv[8] = {x0.x,x0.y,x0.z,x0.w,x1.x,x1.y,x1.z,x1.w};
                #pragma unroll
                for (int k=0;k<4;++k){
                    #pragma unroll
                    for (int qq=0; qq<KW; ++qq){
                        float s = rv[k*S+qq];
                        acc[0][k] = fmaf(s, wa[p*KW+qq],  acc[0][k]);
                        acc[1][k] = fmaf(s, wb2[p*KW+qq], acc[1][k]);
                    }
                }
            }
        }
        #pragma unroll
        for (int j=0;j<2;++j){
            int co = co0+j;
            float inv = bg[co]*rsqrtf(bv[co]+1e-5f);
            float sh  = bb[co] - bm[co]*inv;
            #pragma unroll
            for (int k=0;k<4;++k){
                int ow = ow0+k;
                if (ow < OW)
                    out[((size_t)b*CO+co)*(OH*OW) + oh*OW + ow] = lrelu_f(fmaf(acc[j][k], inv, sh));
            }
        }
    }
}

// ---------------------------------------------------------------------------
// fused = lrelu(h5_flat @ proj_w.T + v @ vproj_w.T + vproj_b)
// ---------------------------------------------------------------------------
__global__ __launch_bounds__(256) void k_head(
    const float* __restrict__ h5, const float* __restrict__ vin,
    const float* __restrict__ proj_w, const float* __restrict__ vproj_w,
    const float* __restrict__ vproj_b, float* __restrict__ fused)
{
    __shared__ __align__(16) float sh[2560];
    __shared__ float sv[9];
    int b = blockIdx.x, tid = threadIdx.x;
    for (int i = tid; i < 2560; i += 256) sh[i] = h5[(size_t)b*2560 + i];
    if (tid < 9) sv[tid] = vin[b*9 + tid];
    __syncthreads();
    const float* pw = proj_w + (size_t)tid*2560;
    float acc = 0.f;
    for (int k=0;k<2560;k+=4){
        float4 s4 = *reinterpret_cast<const float4*>(sh+k);
        float4 w4 = *reinterpret_cast<const float4*>(pw+k);
        acc = fmaf(s4.x,w4.x, fmaf(s4.y,w4.y, fmaf(s4.z,w4.z, fmaf(s4.w,w4.w, acc))));
    }
    float av = 0.f;
    #pragma unroll
    for (int k=0;k<9;++k) av += sv[k]*vproj_w[tid*9+k];
    fused[b*256+tid] = lrelu_f(acc + av + vproj_b[tid]);
}

// ---------------------------------------------------------------------------
// GRU cell: 6 dot-256 per (b, j)
// ---------------------------------------------------------------------------
__global__ __launch_bounds__(256) void k_gru(
    const float* __restrict__ fused, const float* __restrict__ hx,
    const float* __restrict__ wih, const float* __restrict__ whh,
    const float* __restrict__ bih, const float* __restrict__ bhh,
    float* __restrict__ hx_new)
{
    __shared__ __align__(16) float sf[256];
    __shared__ __align__(16) float shx[256];
    int b = blockIdx.x, j = threadIdx.x;
    sf[j]  = fused[b*256+j];
    shx[j] = hx[b*256+j];
    __syncthreads();
    float ga[3], gb[3];
    #pragma unroll
    for (int gi=0; gi<3; ++gi){
        const float* wi = wih + ((size_t)gi*256 + j)*256;
        const float* wh = whh + ((size_t)gi*256 + j)*256;
        float a = 0.f, c = 0.f;
        for (int k=0;k<256;k+=4){
            float4 f4  = *reinterpret_cast<const float4*>(sf+k);
            float4 h4  = *reinterpret_cast<const float4*>(shx+k);
            float4 wi4 = *reinterpret_cast<const float4*>(wi+k);
            float4 wh4 = *reinterpret_cast<const float4*>(wh+k);
            a = fmaf(f4.x,wi4.x, fmaf(f4.y,wi4.y, fmaf(f4.z,wi4.z, fmaf(f4.w,wi4.w, a))));
            c = fmaf(h4.x,wh4.x, fmaf(h4.y,wh4.y, fmaf(h4.z,wh4.z, fmaf(h4.w,wh4.w, c))));
        }
        ga[gi] = a + bih[gi*256+j];
        gb[gi] = c + bhh[gi*256+j];
    }
    float r = 1.f/(1.f+expf(-(ga[0]+gb[0])));
    float z = 1.f/(1.f+expf(-(ga[1]+gb[1])));
    float n = tanhf(ga[2] + r*gb[2]);
    hx_new[b*256+j] = (1.f-z)*n + z*shx[j];
}

// act = lrelu(hx_new) @ fc_w.T  -> (256,4)
__global__ void k_act(const float* __restrict__ hx_new, const float* __restrict__ fc_w,
                      float* __restrict__ act)
{
    int t = blockIdx.x*blockDim.x + threadIdx.x;
    if (t >= 1024) return;
    int b = t >> 2, o = t & 3;
    const float* h = hx_new + b*256;
    const float* w = fc_w + o*256;
    float acc = 0.f;
    for (int k=0;k<256;++k) acc = fmaf(lrelu_f(h[k]), w[k], acc);
    act[t] = acc;
}

extern "C" void kernel_launch(void* const* d_in, const int* in_sizes, int n_in,
                              void* d_out, int out_size, void* d_ws, size_t ws_size,
                              hipStream_t stream)
{
    const float* x      = (const float*)d_in[0];
    const float* vin    = (const float*)d_in[1];
    const float* hx     = (const float*)d_in[2];
    const float* sc0_w  = (const float*)d_in[3];
    const float* bn0g   = (const float*)d_in[4];
    const float* bn0b   = (const float*)d_in[5];
    const float* bn0m   = (const float*)d_in[6];
    const float* bn0v   = (const float*)d_in[7];
    const float* sc1_w  = (const float*)d_in[8];
    const float* bn1g   = (const float*)d_in[9];
    const float* bn1b   = (const float*)d_in[10];
    const float* bn1m   = (const float*)d_in[11];
    const float* bn1v   = (const float*)d_in[12];
    const float* c2_w   = (const float*)d_in[13];
    const float* bn2g   = (const float*)d_in[14];
    const float* bn2b   = (const float*)d_in[15];
    const float* bn2m   = (const float*)d_in[16];
    const float* bn2v   = (const float*)d_in[17];
    const float* c3_w   = (const float*)d_in[18];
    const float* bn3g   = (const float*)d_in[19];
    const float* bn3b   = (const float*)d_in[20];
    const float* bn3m   = (const float*)d_in[21];
    const float* bn3v   = (const float*)d_in[22];
    const float* c4_w   = (const float*)d_in[23];
    const float* bn4g   = (const float*)d_in[24];
    const float* bn4b   = (const float*)d_in[25];
    const float* bn4m   = (const float*)d_in[26];
    const float* bn4v   = (const float*)d_in[27];
    const float* c5_w   = (const float*)d_in[28];
    const float* bn5g   = (const float*)d_in[29];
    const float* bn5b   = (const float*)d_in[30];
    const float* bn5m   = (const float*)d_in[31];
    const float* bn5v   = (const float*)d_in[32];
    const float* proj_w = (const float*)d_in[33];
    const float* vproj_w= (const float*)d_in[34];
    const float* vproj_b= (const float*)d_in[35];
    const float* gru_wih= (const float*)d_in[36];
    const float* gru_whh= (const float*)d_in[37];
    const float* gru_bih= (const float*)d_in[38];
    const float* gru_bhh= (const float*)d_in[39];
    const float* fc_w   = (const float*)d_in[40];

    float* W = (float*)d_ws;
    size_t off = 0;
    int*   map0 = (int*)(W + off); off += 96*192;
    int*   map1 = (int*)(W + off); off += 48*96;
    float* w5t0 = W + off; off += 32*6*25;
    float* w5t1 = W + off; off += 64*32*25;
    float* wt2  = W + off; off += 64*64*9;
    float* wt3  = W + off; off += 64*64*4;
    float* wt4  = W + off; off += 128*64*9;
    float* wt5  = W + off; off += 128*128*9;
    float* bufA = W + off; off += (size_t)256*32*31*63;   // h0 / h2 / h4 / fused
    float* bufB = W + off; off += (size_t)256*64*15*31;   // h1 / h3 / h5

    // small precompute
    k_idxmap<<<72, 256, 0, stream>>>(map0, 64, 128, 64, 96*192);
    k_idxmap<<<18, 256, 0, stream>>>(map1, 31,  63, 32, 48*96);
    k_w5<<<(32*6*25 +255)/256, 256, 0, stream>>>(sc0_w, w5t0, 32, 6);
    k_w5<<<(64*32*25+255)/256, 256, 0, stream>>>(sc1_w, w5t1, 64, 32);
    k_wT<<<(64*64*9  +255)/256, 256, 0, stream>>>(c2_w, wt2, 64,  64*9);
    k_wT<<<(64*64*4  +255)/256, 256, 0, stream>>>(c3_w, wt3, 64,  64*4);
    k_wT<<<(128*64*9 +255)/256, 256, 0, stream>>>(c4_w, wt4, 128, 64*9);
    k_wT<<<(128*128*9+255)/256, 256, 0, stream>>>(c5_w, wt5, 128, 128*9);

    // backbone
    k_sconv<6,32,31,63,192,64*128><<<256*31, 256, 0, stream>>>(x,    map0, w5t0, bn0g,bn0b,bn0m,bn0v, bufA);
    k_sconv<32,64,15,31,96,31*63><<<256*15, 256, 0, stream>>>(bufA, map1, w5t1, bn1g,bn1b,bn1m,bn1v, bufB);
    k_conv<64,64,3,3,1,15,31,32,13,29><<<256,256,0,stream>>>(bufB, wt2, bn2g,bn2b,bn2m,bn2v, bufA);
    k_conv<64,64,2,2,2,13,29,32,6,14><<<256,256,0,stream>>>(bufA, wt3, bn3g,bn3b,bn3m,bn3v, bufB);
    k_conv<64,128,3,3,1,6,14,16,4,12><<<256,256,0,stream>>>(bufB, wt4, bn4g,bn4b,bn4m,bn4v, bufA);
    k_conv<128,128,3,3,1,4,12,12,2,10><<<256,256,0,stream>>>(bufA, wt5, bn5g,bn5b,bn5m,bn5v, bufB);

    // head
    k_head<<<256,256,0,stream>>>(bufB, vin, proj_w, vproj_w, vproj_b, bufA);
    float* outp = (float*)d_out;
    k_gru<<<256,256,0,stream>>>(bufA, hx, gru_wih, gru_whh, gru_bih, gru_bhh, outp + 1024);
    k_act<<<4,256,0,stream>>>(outp + 1024, fc_w, outp);
}

// Round 5
// 1713.231 us; speedup vs baseline: 3.7145x; 3.6336x over previous
//
#include <hip/hip_runtime.h>
#include <math.h>

#define PI_F 3.14159265358979323846f

__device__ __forceinline__ float lrelu_f(float x){ return x >= 0.f ? x : 0.05f*x; }

// ---------------------------------------------------------------------------
// Index map: xu flat index -> lat*W + lon  (pure-gather form of grid_sample)
// xu is the C-order reshape of (H_out, W_out, Kh, Kw):
//   flat = oh*(Wo*9) + ow*9 + kh*3 + kw
// ---------------------------------------------------------------------------
__global__ void k_idxmap(int* __restrict__ map, int H, int W, int Wo, int total)
{
    int i = blockIdx.x*blockDim.x + threadIdx.x;
    if (i >= total) return;
    int oh  = i / (Wo*9);
    int rem = i % (Wo*9);
    int ow  = rem / 9;
    int r2  = rem % 9;
    int kh  = r2/3, kw = r2%3;
    int ihc = min(oh*2, H-1);
    int lat = min(max(ihc + kh - 1, 0), H-1);
    float phi = ((float)lat + 0.5f)/(float)H * PI_F - 0.5f*PI_F;
    float ca  = fmaxf(fabsf(cosf(phi)), 1e-3f);
    float d   = fminf(0.8f/ca, 4.0f);
    float jw  = (float)((ow*2) % W);
    float lonf = rintf(jw + d*(float)(kw-1));   // np.round = half-to-even
    int lon = (int)lonf % W; if (lon < 0) lon += W;
    map[i] = lat*W + lon;
}

// ---------------------------------------------------------------------------
// Fold avg_pool3(conv3x3(.)) into an effective 5x5 stride-3 kernel:
//   W5[u][v] = (1/9) * sum_{p,q in [0,2], u-p in [0,2], v-q in [0,2]} w[p][q]
// Stored TRANSPOSED: w5t[(ci*25 + u*5+v)*CO + co] for coalesced lane loads.
// ---------------------------------------------------------------------------
__global__ void k_w5(const float* __restrict__ w3, float* __restrict__ w5t, int CO, int CI)
{
    int i = blockIdx.x*blockDim.x + threadIdx.x;
    if (i >= CO*CI*25) return;
    int v = i % 5, u = (i/5) % 5;
    int cc = i / 25;                 // cc = co*CI + ci (OIHW order)
    int ci = cc % CI, co = cc / CI;
    const float* w = w3 + cc*9;
    int p0 = max(0, u-2), p1 = min(2, u);
    int q0 = max(0, v-2), q1 = min(2, v);
    float s = 0.f;
    for (int p=p0;p<=p1;++p)
        for (int q=q0;q<=q1;++q) s += w[p*3+q];
    w5t[(ci*25 + u*5 + v)*CO + co] = s*(1.0f/9.0f);
}

// transpose OIHW -> [ci*KH*KW][CO] for coalesced weight loads
__global__ void k_wT(const float* __restrict__ w, float* __restrict__ wt, int CO, int CIK)
{
    int i = blockIdx.x*blockDim.x + threadIdx.x;
    if (i >= CO*CIK) return;
    int co = i / CIK, j = i % CIK;
    wt[j*CO + co] = w[i];
}

// ---------------------------------------------------------------------------
// Fused sphere-conv: gather -> 5x5 stride-3 conv -> BN -> lrelu
// One block per (b, oh). Gathered slab (5 rows of xu, all cols) in LDS.
// Thread = (co-pair, ow-quad). REGISTER-PRESSURE DISCIPLINE (R4 post-mortem):
// ci/u loops are unroll-1 and weights are loaded per (u,vi) just before use —
// the previous 50-float per-ci weight preload under a fully-unrolled ci loop
// spilled (VGPR=256, 14 GB scratch traffic, 3% VALUBusy).
// ---------------------------------------------------------------------------
template<int CI,int CO,int OH,int OW,int RW,int IPLANE>
__global__ __launch_bounds__(256) void k_sconv(
    const float* __restrict__ in, const int* __restrict__ map,
    const float* __restrict__ w5t,
    const float* __restrict__ bg, const float* __restrict__ bb,
    const float* __restrict__ bm, const float* __restrict__ bv,
    float* __restrict__ out)
{
    constexpr int NCP = CO/2;
    constexpr int NQ  = (OW+3)/4;
    static_assert(NCP*NQ == 256, "thread mapping must cover block exactly");
    __shared__ __align__(16) float sx[CI*5*RW + 16];

    int b  = blockIdx.x / OH;
    int oh = blockIdx.x % OH;
    int tid = threadIdx.x;
    const float* xb = in + (size_t)b*CI*IPLANE;
    int r0 = oh*3;
    for (int i = tid; i < CI*5*RW; i += 256){
        int c  = i % RW;
        int t  = i / RW;
        int rr = t % 5;
        int ci = t / 5;
        int m  = map[(r0+rr)*RW + c];
        sx[(ci*5+rr)*RW + c] = xb[(size_t)ci*IPLANE + m];
    }
    __syncthreads();

    int cp  = tid % NCP;
    int q   = tid / NCP;
    int co0 = cp*2;
    int ow0 = q*4;
    float acc0[4] = {0.f,0.f,0.f,0.f};
    float acc1[4] = {0.f,0.f,0.f,0.f};
    #pragma unroll 1
    for (int ci=0; ci<CI; ++ci){
        #pragma unroll 1
        for (int u=0;u<5;++u){
            const float* row  = &sx[(ci*5+u)*RW + ow0*3];
            const float* wrow = w5t + (ci*25 + u*5)*CO + co0;
            float4 a0 = *reinterpret_cast<const float4*>(row);
            float4 a1 = *reinterpret_cast<const float4*>(row+4);
            float4 a2 = *reinterpret_cast<const float4*>(row+8);
            float4 a3 = *reinterpret_cast<const float4*>(row+12);
            float rv[16] = {a0.x,a0.y,a0.z,a0.w, a1.x,a1.y,a1.z,a1.w,
                            a2.x,a2.y,a2.z,a2.w, a3.x,a3.y,a3.z,a3.w};
            #pragma unroll
            for (int vi=0; vi<5; ++vi){
                float2 w2 = *reinterpret_cast<const float2*>(wrow + vi*CO);
                #pragma unroll
                for (int k=0;k<4;++k){
                    float s = rv[k*3+vi];
                    acc0[k] = fmaf(s, w2.x, acc0[k]);
                    acc1[k] = fmaf(s, w2.y, acc1[k]);
                }
            }
        }
    }
    #pragma unroll
    for (int j=0;j<2;++j){
        int co = co0 + j;
        float inv = bg[co]*rsqrtf(bv[co] + 1e-5f);
        float sh  = bb[co] - bm[co]*inv;
        #pragma unroll
        for (int k=0;k<4;++k){
            int ow = ow0 + k;
            float a = j ? acc1[k] : acc0[k];
            if (ow < OW)
                out[((size_t)b*CO + co)*(OH*OW) + oh*OW + ow] = lrelu_f(fmaf(a, inv, sh));
        }
    }
}

// ---------------------------------------------------------------------------
// Direct VALID conv + BN + lrelu. One block per batch item; whole input
// plane staged in LDS (row-padded to IWP for aligned float4 reads).
// Same register discipline: unroll-1 ci/p loops, per-(p,q) weight loads.
// ---------------------------------------------------------------------------
template<int CI,int CO,int KH,int KW,int S,int IH,int IW,int IWP,int OH,int OW>
__global__ __launch_bounds__(256) void k_conv(
    const float* __restrict__ in, const float* __restrict__ wt,
    const float* __restrict__ bg, const float* __restrict__ bb,
    const float* __restrict__ bm, const float* __restrict__ bv,
    float* __restrict__ out)
{
    __shared__ __align__(16) float sx[CI*IH*IWP + 16];
    int b = blockIdx.x, tid = threadIdx.x;
    const float* ib = in + (size_t)b*CI*IH*IW;
    for (int i = tid; i < CI*IH*IW; i += 256){
        int c = i % IW;
        int t = i / IW;
        sx[t*IWP + c] = ib[i];
    }
    __syncthreads();
    constexpr int OWT = (OW+3)/4;
    constexpr int NT  = (CO/2)*OH*OWT;
    for (int t = tid; t < NT; t += 256){
        int owt = t % OWT;
        int r   = t / OWT;
        int oh  = r % OH;
        int cp  = r / OH;
        int co0 = cp*2;
        int ow0 = owt*4;
        float acc0[4] = {0.f,0.f,0.f,0.f};
        float acc1[4] = {0.f,0.f,0.f,0.f};
        #pragma unroll 1
        for (int ci=0; ci<CI; ++ci){
            #pragma unroll 1
            for (int p=0;p<KH;++p){
                const float* row  = &sx[(ci*IH + oh*S + p)*IWP + ow0*S];
                const float* wrow = wt + (ci*KH*KW + p*KW)*CO + co0;
                float4 x0 = *reinterpret_cast<const float4*>(row);
                float4 x1 = *reinterpret_cast<const float4*>(row+4);
                float rv[8] = {x0.x,x0.y,x0.z,x0.w,x1.x,x1.y,x1.z,x1.w};
                #pragma unroll
                for (int qq=0; qq<KW; ++qq){
                    float2 w2 = *reinterpret_cast<const float2*>(wrow + qq*CO);
                    #pragma unroll
                    for (int k=0;k<4;++k){
                        float s = rv[k*S+qq];
                        acc0[k] = fmaf(s, w2.x, acc0[k]);
                        acc1[k] = fmaf(s, w2.y, acc1[k]);
                    }
                }
            }
        }
        #pragma unroll
        for (int j=0;j<2;++j){
            int co = co0+j;
            float inv = bg[co]*rsqrtf(bv[co]+1e-5f);
            float sh  = bb[co] - bm[co]*inv;
            #pragma unroll
            for (int k=0;k<4;++k){
                int ow = ow0+k;
                float a = j ? acc1[k] : acc0[k];
                if (ow < OW)
                    out[((size_t)b*CO+co)*(OH*OW) + oh*OW + ow] = lrelu_f(fmaf(a, inv, sh));
            }
        }
    }
}

// ---------------------------------------------------------------------------
// fused = lrelu(h5_flat @ proj_w.T + v @ vproj_w.T + vproj_b)
// ---------------------------------------------------------------------------
__global__ __launch_bounds__(256) void k_head(
    const float* __restrict__ h5, const float* __restrict__ vin,
    const float* __restrict__ proj_w, const float* __restrict__ vproj_w,
    const float* __restrict__ vproj_b, float* __restrict__ fused)
{
    __shared__ __align__(16) float sh[2560];
    __shared__ float sv[9];
    int b = blockIdx.x, tid = threadIdx.x;
    for (int i = tid; i < 2560; i += 256) sh[i] = h5[(size_t)b*2560 + i];
    if (tid < 9) sv[tid] = vin[b*9 + tid];
    __syncthreads();
    const float* pw = proj_w + (size_t)tid*2560;
    float acc = 0.f;
    for (int k=0;k<2560;k+=4){
        float4 s4 = *reinterpret_cast<const float4*>(sh+k);
        float4 w4 = *reinterpret_cast<const float4*>(pw+k);
        acc = fmaf(s4.x,w4.x, fmaf(s4.y,w4.y, fmaf(s4.z,w4.z, fmaf(s4.w,w4.w, acc))));
    }
    float av = 0.f;
    #pragma unroll
    for (int k=0;k<9;++k) av += sv[k]*vproj_w[tid*9+k];
    fused[b*256+tid] = lrelu_f(acc + av + vproj_b[tid]);
}

// ---------------------------------------------------------------------------
// GRU cell: 6 dot-256 per (b, j)
// ---------------------------------------------------------------------------
__global__ __launch_bounds__(256) void k_gru(
    const float* __restrict__ fused, const float* __restrict__ hx,
    const float* __restrict__ wih, const float* __restrict__ whh,
    const float* __restrict__ bih, const float* __restrict__ bhh,
    float* __restrict__ hx_new)
{
    __shared__ __align__(16) float sf[256];
    __shared__ __align__(16) float shx[256];
    int b = blockIdx.x, j = threadIdx.x;
    sf[j]  = fused[b*256+j];
    shx[j] = hx[b*256+j];
    __syncthreads();
    float ga[3], gb[3];
    #pragma unroll
    for (int gi=0; gi<3; ++gi){
        const float* wi = wih + ((size_t)gi*256 + j)*256;
        const float* wh = whh + ((size_t)gi*256 + j)*256;
        float a = 0.f, c = 0.f;
        for (int k=0;k<256;k+=4){
            float4 f4  = *reinterpret_cast<const float4*>(sf+k);
            float4 h4  = *reinterpret_cast<const float4*>(shx+k);
            float4 wi4 = *reinterpret_cast<const float4*>(wi+k);
            float4 wh4 = *reinterpret_cast<const float4*>(wh+k);
            a = fmaf(f4.x,wi4.x, fmaf(f4.y,wi4.y, fmaf(f4.z,wi4.z, fmaf(f4.w,wi4.w, a))));
            c = fmaf(h4.x,wh4.x, fmaf(h4.y,wh4.y, fmaf(h4.z,wh4.z, fmaf(h4.w,wh4.w, c))));
        }
        ga[gi] = a + bih[gi*256+j];
        gb[gi] = c + bhh[gi*256+j];
    }
    float r = 1.f/(1.f+expf(-(ga[0]+gb[0])));
    float z = 1.f/(1.f+expf(-(ga[1]+gb[1])));
    float n = tanhf(ga[2] + r*gb[2]);
    hx_new[b*256+j] = (1.f-z)*n + z*shx[j];
}

// act = lrelu(hx_new) @ fc_w.T  -> (256,4)
__global__ void k_act(const float* __restrict__ hx_new, const float* __restrict__ fc_w,
                      float* __restrict__ act)
{
    int t = blockIdx.x*blockDim.x + threadIdx.x;
    if (t >= 1024) return;
    int b = t >> 2, o = t & 3;
    const float* h = hx_new + b*256;
    const float* w = fc_w + o*256;
    float acc = 0.f;
    for (int k=0;k<256;++k) acc = fmaf(lrelu_f(h[k]), w[k], acc);
    act[t] = acc;
}

extern "C" void kernel_launch(void* const* d_in, const int* in_sizes, int n_in,
                              void* d_out, int out_size, void* d_ws, size_t ws_size,
                              hipStream_t stream)
{
    const float* x      = (const float*)d_in[0];
    const float* vin    = (const float*)d_in[1];
    const float* hx     = (const float*)d_in[2];
    const float* sc0_w  = (const float*)d_in[3];
    const float* bn0g   = (const float*)d_in[4];
    const float* bn0b   = (const float*)d_in[5];
    const float* bn0m   = (const float*)d_in[6];
    const float* bn0v   = (const float*)d_in[7];
    const float* sc1_w  = (const float*)d_in[8];
    const float* bn1g   = (const float*)d_in[9];
    const float* bn1b   = (const float*)d_in[10];
    const float* bn1m   = (const float*)d_in[11];
    const float* bn1v   = (const float*)d_in[12];
    const float* c2_w   = (const float*)d_in[13];
    const float* bn2g   = (const float*)d_in[14];
    const float* bn2b   = (const float*)d_in[15];
    const float* bn2m   = (const float*)d_in[16];
    const float* bn2v   = (const float*)d_in[17];
    const float* c3_w   = (const float*)d_in[18];
    const float* bn3g   = (const float*)d_in[19];
    const float* bn3b   = (const float*)d_in[20];
    const float* bn3m   = (const float*)d_in[21];
    const float* bn3v   = (const float*)d_in[22];
    const float* c4_w   = (const float*)d_in[23];
    const float* bn4g   = (const float*)d_in[24];
    const float* bn4b   = (const float*)d_in[25];
    const float* bn4m   = (const float*)d_in[26];
    const float* bn4v   = (const float*)d_in[27];
    const float* c5_w   = (const float*)d_in[28];
    const float* bn5g   = (const float*)d_in[29];
    const float* bn5b   = (const float*)d_in[30];
    const float* bn5m   = (const float*)d_in[31];
    const float* bn5v   = (const float*)d_in[32];
    const float* proj_w = (const float*)d_in[33];
    const float* vproj_w= (const float*)d_in[34];
    const float* vproj_b= (const float*)d_in[35];
    const float* gru_wih= (const float*)d_in[36];
    const float* gru_whh= (const float*)d_in[37];
    const float* gru_bih= (const float*)d_in[38];
    const float* gru_bhh= (const float*)d_in[39];
    const float* fc_w   = (const float*)d_in[40];

    float* W = (float*)d_ws;
    size_t off = 0;
    int*   map0 = (int*)(W + off); off += 96*192;
    int*   map1 = (int*)(W + off); off += 48*96;
    float* w5t0 = W + off; off += 32*6*25;
    float* w5t1 = W + off; off += 64*32*25;
    float* wt2  = W + off; off += 64*64*9;
    float* wt3  = W + off; off += 64*64*4;
    float* wt4  = W + off; off += 128*64*9;
    float* wt5  = W + off; off += 128*128*9;
    float* bufA = W + off; off += (size_t)256*32*31*63;   // h0 / h2 / h4 / fused
    float* bufB = W + off; off += (size_t)256*64*15*31;   // h1 / h3 / h5

    // small precompute
    k_idxmap<<<72, 256, 0, stream>>>(map0, 64, 128, 64, 96*192);
    k_idxmap<<<18, 256, 0, stream>>>(map1, 31,  63, 32, 48*96);
    k_w5<<<(32*6*25 +255)/256, 256, 0, stream>>>(sc0_w, w5t0, 32, 6);
    k_w5<<<(64*32*25+255)/256, 256, 0, stream>>>(sc1_w, w5t1, 64, 32);
    k_wT<<<(64*64*9  +255)/256, 256, 0, stream>>>(c2_w, wt2, 64,  64*9);
    k_wT<<<(64*64*4  +255)/256, 256, 0, stream>>>(c3_w, wt3, 64,  64*4);
    k_wT<<<(128*64*9 +255)/256, 256, 0, stream>>>(c4_w, wt4, 128, 64*9);
    k_wT<<<(128*128*9+255)/256, 256, 0, stream>>>(c5_w, wt5, 128, 128*9);

    // backbone
    k_sconv<6,32,31,63,192,64*128><<<256*31, 256, 0, stream>>>(x,    map0, w5t0, bn0g,bn0b,bn0m,bn0v, bufA);
    k_sconv<32,64,15,31,96,31*63><<<256*15, 256, 0, stream>>>(bufA, map1, w5t1, bn1g,bn1b,bn1m,bn1v, bufB);
    k_conv<64,64,3,3,1,15,31,32,13,29><<<256,256,0,stream>>>(bufB, wt2, bn2g,bn2b,bn2m,bn2v, bufA);
    k_conv<64,64,2,2,2,13,29,32,6,14><<<256,256,0,stream>>>(bufA, wt3, bn3g,bn3b,bn3m,bn3v, bufB);
    k_conv<64,128,3,3,1,6,14,16,4,12><<<256,256,0,stream>>>(bufB, wt4, bn4g,bn4b,bn4m,bn4v, bufA);
    k_conv<128,128,3,3,1,4,12,12,2,10><<<256,256,0,stream>>>(bufA, wt5, bn5g,bn5b,bn5m,bn5v, bufB);

    // head
    k_head<<<256,256,0,stream>>>(bufB, vin, proj_w, vproj_w, vproj_b, bufA);
    float* outp = (float*)d_out;
    k_gru<<<256,256,0,stream>>>(bufA, hx, gru_wih, gru_whh, gru_bih, gru_bhh, outp + 1024);
    k_act<<<4,256,0,stream>>>(outp + 1024, fc_w, outp);
}

// Round 6
// 1264.972 us; speedup vs baseline: 5.0307x; 1.3544x over previous
//
#include <hip/hip_runtime.h>
#include <math.h>

#define PI_F 3.14159265358979323846f

__device__ __forceinline__ float lrelu_f(float x){ return x >= 0.f ? x : 0.05f*x; }

// ---------------------------------------------------------------------------
// Index map: xu flat index -> lat*W + lon  (pure-gather form of grid_sample)
// xu is the C-order reshape of (H_out, W_out, Kh, Kw):
//   flat = oh*(Wo*9) + ow*9 + kh*3 + kw
// ---------------------------------------------------------------------------
__global__ void k_idxmap(int* __restrict__ map, int H, int W, int Wo, int total)
{
    int i = blockIdx.x*blockDim.x + threadIdx.x;
    if (i >= total) return;
    int oh  = i / (Wo*9);
    int rem = i % (Wo*9);
    int ow  = rem / 9;
    int r2  = rem % 9;
    int kh  = r2/3, kw = r2%3;
    int ihc = min(oh*2, H-1);
    int lat = min(max(ihc + kh - 1, 0), H-1);
    float phi = ((float)lat + 0.5f)/(float)H * PI_F - 0.5f*PI_F;
    float ca  = fmaxf(fabsf(cosf(phi)), 1e-3f);
    float d   = fminf(0.8f/ca, 4.0f);
    float jw  = (float)((ow*2) % W);
    float lonf = rintf(jw + d*(float)(kw-1));   // np.round = half-to-even
    int lon = (int)lonf % W; if (lon < 0) lon += W;
    map[i] = lat*W + lon;
}

// ---------------------------------------------------------------------------
// Fold avg_pool3(conv3x3(.)) into an effective 5x5 stride-3 kernel:
//   W5[u][v] = (1/9) * sum_{p,q in [0,2], u-p in [0,2], v-q in [0,2]} w[p][q]
// Stored TRANSPOSED: w5t[(ci*25 + u*5+v)*CO + co] for coalesced lane loads.
// ---------------------------------------------------------------------------
__global__ void k_w5(const float* __restrict__ w3, float* __restrict__ w5t, int CO, int CI)
{
    int i = blockIdx.x*blockDim.x + threadIdx.x;
    if (i >= CO*CI*25) return;
    int v = i % 5, u = (i/5) % 5;
    int cc = i / 25;                 // cc = co*CI + ci (OIHW order)
    int ci = cc % CI, co = cc / CI;
    const float* w = w3 + cc*9;
    int p0 = max(0, u-2), p1 = min(2, u);
    int q0 = max(0, v-2), q1 = min(2, v);
    float s = 0.f;
    for (int p=p0;p<=p1;++p)
        for (int q=q0;q<=q1;++q) s += w[p*3+q];
    w5t[(ci*25 + u*5 + v)*CO + co] = s*(1.0f/9.0f);
}

// transpose OIHW -> [ci*KH*KW][CO] for coalesced weight loads
__global__ void k_wT(const float* __restrict__ w, float* __restrict__ wt, int CO, int CIK)
{
    int i = blockIdx.x*blockDim.x + threadIdx.x;
    if (i >= CO*CIK) return;
    int co = i / CIK, j = i % CIK;
    wt[j*CO + co] = w[i];
}

// ---------------------------------------------------------------------------
// Fused sphere-conv: gather -> 5x5 stride-3 conv -> BN -> lrelu
// One block per (b, oh). Gathered slab staged in LDS in ci-chunks of CICH
// channels (R5 post-mortem: 62 KB LDS capped residency at 2 blocks/CU ->
// 22% occupancy, latency-bound at VALUBusy 41%). Accumulators persist
// across chunks; ci summation order unchanged (bit-identical).
// Register discipline (R4): unroll-1 ci/u loops, JIT weight loads.
// ---------------------------------------------------------------------------
template<int CI,int CO,int OH,int OW,int RW,int IPLANE,int CICH>
__global__ __launch_bounds__(256) void k_sconv(
    const float* __restrict__ in, const int* __restrict__ map,
    const float* __restrict__ w5t,
    const float* __restrict__ bg, const float* __restrict__ bb,
    const float* __restrict__ bm, const float* __restrict__ bv,
    float* __restrict__ out)
{
    constexpr int NCP = CO/2;
    constexpr int NQ  = (OW+3)/4;
    static_assert(NCP*NQ == 256, "thread mapping must cover block exactly");
    static_assert(CI % CICH == 0, "ci chunking must divide CI");
    __shared__ __align__(16) float sx[CICH*5*RW + 16];

    int b  = blockIdx.x / OH;
    int oh = blockIdx.x % OH;
    int tid = threadIdx.x;
    const float* xb = in + (size_t)b*CI*IPLANE;
    int r0 = oh*3;

    int cp  = tid % NCP;
    int q   = tid / NCP;
    int co0 = cp*2;
    int ow0 = q*4;
    float acc0[4] = {0.f,0.f,0.f,0.f};
    float acc1[4] = {0.f,0.f,0.f,0.f};

    for (int cc = 0; cc < CI; cc += CICH){
        if (cc) __syncthreads();
        for (int i = tid; i < CICH*5*RW; i += 256){
            int c   = i % RW;
            int t   = i / RW;
            int rr  = t % 5;
            int cil = t / 5;
            int m   = map[(r0+rr)*RW + c];
            sx[(cil*5+rr)*RW + c] = xb[(size_t)(cc+cil)*IPLANE + m];
        }
        __syncthreads();

        #pragma unroll 1
        for (int cil=0; cil<CICH; ++cil){
            #pragma unroll 1
            for (int u=0;u<5;++u){
                const float* row  = &sx[(cil*5+u)*RW + ow0*3];
                const float* wrow = w5t + ((cc+cil)*25 + u*5)*CO + co0;
                float4 a0 = *reinterpret_cast<const float4*>(row);
                float4 a1 = *reinterpret_cast<const float4*>(row+4);
                float4 a2 = *reinterpret_cast<const float4*>(row+8);
                float4 a3 = *reinterpret_cast<const float4*>(row+12);
                float rv[16] = {a0.x,a0.y,a0.z,a0.w, a1.x,a1.y,a1.z,a1.w,
                                a2.x,a2.y,a2.z,a2.w, a3.x,a3.y,a3.z,a3.w};
                #pragma unroll
                for (int vi=0; vi<5; ++vi){
                    float2 w2 = *reinterpret_cast<const float2*>(wrow + vi*CO);
                    #pragma unroll
                    for (int k=0;k<4;++k){
                        float s = rv[k*3+vi];
                        acc0[k] = fmaf(s, w2.x, acc0[k]);
                        acc1[k] = fmaf(s, w2.y, acc1[k]);
                    }
                }
            }
        }
    }
    #pragma unroll
    for (int j=0;j<2;++j){
        int co = co0 + j;
        float inv = bg[co]*rsqrtf(bv[co] + 1e-5f);
        float sh  = bb[co] - bm[co]*inv;
        #pragma unroll
        for (int k=0;k<4;++k){
            int ow = ow0 + k;
            float a = j ? acc1[k] : acc0[k];
            if (ow < OW)
                out[((size_t)b*CO + co)*(OH*OW) + oh*OW + ow] = lrelu_f(fmaf(a, inv, sh));
        }
    }
}

// ---------------------------------------------------------------------------
// Direct VALID conv + BN + lrelu, occupancy-restructured (R5):
//  - ci-chunked LDS staging (CICH channels per pass, acc persists)
//  - co-split across CSPLIT blocks per batch item (bigger grid)
//  - KTILES output tiles per thread when NT > 256 (compile-time indices)
// ---------------------------------------------------------------------------
template<int CI,int CO,int KH,int KW,int S,int IH,int IW,int IWP,int OH,int OW,
         int CICH,int CSPLIT,int KTILES>
__global__ __launch_bounds__(256) void k_conv(
    const float* __restrict__ in, const float* __restrict__ wt,
    const float* __restrict__ bg, const float* __restrict__ bb,
    const float* __restrict__ bm, const float* __restrict__ bv,
    float* __restrict__ out)
{
    constexpr int OWT = (OW+3)/4;
    constexpr int COB = CO/CSPLIT;
    constexpr int NCP = COB/2;
    constexpr int NT  = NCP*OH*OWT;
    static_assert(NT <= KTILES*256, "KTILES too small");
    static_assert(CI % CICH == 0, "ci chunking must divide CI");
    __shared__ __align__(16) float sx[CICH*IH*IWP + 16];

    int b    = blockIdx.x / CSPLIT;
    int sp   = blockIdx.x % CSPLIT;
    int cob0 = sp*COB;
    int tid  = threadIdx.x;

    float acc[KTILES][2][4] = {};

    for (int cc = 0; cc < CI; cc += CICH){
        if (cc) __syncthreads();
        const float* ibc = in + ((size_t)b*CI + cc)*IH*IW;
        for (int i = tid; i < CICH*IH*IW; i += 256){
            int c = i % IW;
            int t = i / IW;
            sx[t*IWP + c] = ibc[i];
        }
        __syncthreads();

        #pragma unroll
        for (int kt=0; kt<KTILES; ++kt){
            int t = tid + kt*256;
            if (t < NT){
                int owt = t % OWT;
                int r   = t / OWT;
                int oh  = r % OH;
                int cp  = r / OH;
                int co0 = cob0 + cp*2;
                int ow0 = owt*4;
                #pragma unroll 1
                for (int cil=0; cil<CICH; ++cil){
                    #pragma unroll 1
                    for (int p=0;p<KH;++p){
                        const float* row  = &sx[(cil*IH + oh*S + p)*IWP + ow0*S];
                        const float* wrow = wt + ((cc+cil)*KH*KW + p*KW)*CO + co0;
                        float4 x0 = *reinterpret_cast<const float4*>(row);
                        float4 x1 = *reinterpret_cast<const float4*>(row+4);
                        float rv[8] = {x0.x,x0.y,x0.z,x0.w,x1.x,x1.y,x1.z,x1.w};
                        #pragma unroll
                        for (int qq=0; qq<KW; ++qq){
                            float2 w2 = *reinterpret_cast<const float2*>(wrow + qq*CO);
                            #pragma unroll
                            for (int k=0;k<4;++k){
                                float s = rv[k*S+qq];
                                acc[kt][0][k] = fmaf(s, w2.x, acc[kt][0][k]);
                                acc[kt][1][k] = fmaf(s, w2.y, acc[kt][1][k]);
                            }
                        }
                    }
                }
            }
        }
    }

    #pragma unroll
    for (int kt=0; kt<KTILES; ++kt){
        int t = tid + kt*256;
        if (t < NT){
            int owt = t % OWT;
            int r   = t / OWT;
            int oh  = r % OH;
            int cp  = r / OH;
            int co0 = cob0 + cp*2;
            int ow0 = owt*4;
            #pragma unroll
            for (int j=0;j<2;++j){
                int co = co0+j;
                float inv = bg[co]*rsqrtf(bv[co]+1e-5f);
                float sh  = bb[co] - bm[co]*inv;
                #pragma unroll
                for (int k=0;k<4;++k){
                    int ow = ow0+k;
                    if (ow < OW)
                        out[((size_t)b*CO+co)*(OH*OW) + oh*OW + ow] =
                            lrelu_f(fmaf(acc[kt][j][k], inv, sh));
                }
            }
        }
    }
}

// ---------------------------------------------------------------------------
// fused = lrelu(h5_flat @ proj_w.T + v @ vproj_w.T + vproj_b)
// ---------------------------------------------------------------------------
__global__ __launch_bounds__(256) void k_head(
    const float* __restrict__ h5, const float* __restrict__ vin,
    const float* __restrict__ proj_w, const float* __restrict__ vproj_w,
    const float* __restrict__ vproj_b, float* __restrict__ fused)
{
    __shared__ __align__(16) float sh[2560];
    __shared__ float sv[9];
    int b = blockIdx.x, tid = threadIdx.x;
    for (int i = tid; i < 2560; i += 256) sh[i] = h5[(size_t)b*2560 + i];
    if (tid < 9) sv[tid] = vin[b*9 + tid];
    __syncthreads();
    const float* pw = proj_w + (size_t)tid*2560;
    float acc = 0.f;
    for (int k=0;k<2560;k+=4){
        float4 s4 = *reinterpret_cast<const float4*>(sh+k);
        float4 w4 = *reinterpret_cast<const float4*>(pw+k);
        acc = fmaf(s4.x,w4.x, fmaf(s4.y,w4.y, fmaf(s4.z,w4.z, fmaf(s4.w,w4.w, acc))));
    }
    float av = 0.f;
    #pragma unroll
    for (int k=0;k<9;++k) av += sv[k]*vproj_w[tid*9+k];
    fused[b*256+tid] = lrelu_f(acc + av + vproj_b[tid]);
}

// ---------------------------------------------------------------------------
// GRU cell: 6 dot-256 per (b, j)
// ---------------------------------------------------------------------------
__global__ __launch_bounds__(256) void k_gru(
    const float* __restrict__ fused, const float* __restrict__ hx,
    const float* __restrict__ wih, const float* __restrict__ whh,
    const float* __restrict__ bih, const float* __restrict__ bhh,
    float* __restrict__ hx_new)
{
    __shared__ __align__(16) float sf[256];
    __shared__ __align__(16) float shx[256];
    int b = blockIdx.x, j = threadIdx.x;
    sf[j]  = fused[b*256+j];
    shx[j] = hx[b*256+j];
    __syncthreads();
    float ga[3], gb[3];
    #pragma unroll
    for (int gi=0; gi<3; ++gi){
        const float* wi = wih + ((size_t)gi*256 + j)*256;
        const float* wh = whh + ((size_t)gi*256 + j)*256;
        float a = 0.f, c = 0.f;
        for (int k=0;k<256;k+=4){
            float4 f4  = *reinterpret_cast<const float4*>(sf+k);
            float4 h4  = *reinterpret_cast<const float4*>(shx+k);
            float4 wi4 = *reinterpret_cast<const float4*>(wi+k);
            float4 wh4 = *reinterpret_cast<const float4*>(wh+k);
            a = fmaf(f4.x,wi4.x, fmaf(f4.y,wi4.y, fmaf(f4.z,wi4.z, fmaf(f4.w,wi4.w, a))));
            c = fmaf(h4.x,wh4.x, fmaf(h4.y,wh4.y, fmaf(h4.z,wh4.z, fmaf(h4.w,wh4.w, c))));
        }
        ga[gi] = a + bih[gi*256+j];
        gb[gi] = c + bhh[gi*256+j];
    }
    float r = 1.f/(1.f+expf(-(ga[0]+gb[0])));
    float z = 1.f/(1.f+expf(-(ga[1]+gb[1])));
    float n = tanhf(ga[2] + r*gb[2]);
    hx_new[b*256+j] = (1.f-z)*n + z*shx[j];
}

// act = lrelu(hx_new) @ fc_w.T  -> (256,4)
__global__ void k_act(const float* __restrict__ hx_new, const float* __restrict__ fc_w,
                      float* __restrict__ act)
{
    int t = blockIdx.x*blockDim.x + threadIdx.x;
    if (t >= 1024) return;
    int b = t >> 2, o = t & 3;
    const float* h = hx_new + b*256;
    const float* w = fc_w + o*256;
    float acc = 0.f;
    for (int k=0;k<256;++k) acc = fmaf(lrelu_f(h[k]), w[k], acc);
    act[t] = acc;
}

extern "C" void kernel_launch(void* const* d_in, const int* in_sizes, int n_in,
                              void* d_out, int out_size, void* d_ws, size_t ws_size,
                              hipStream_t stream)
{
    const float* x      = (const float*)d_in[0];
    const float* vin    = (const float*)d_in[1];
    const float* hx     = (const float*)d_in[2];
    const float* sc0_w  = (const float*)d_in[3];
    const float* bn0g   = (const float*)d_in[4];
    const float* bn0b   = (const float*)d_in[5];
    const float* bn0m   = (const float*)d_in[6];
    const float* bn0v   = (const float*)d_in[7];
    const float* sc1_w  = (const float*)d_in[8];
    const float* bn1g   = (const float*)d_in[9];
    const float* bn1b   = (const float*)d_in[10];
    const float* bn1m   = (const float*)d_in[11];
    const float* bn1v   = (const float*)d_in[12];
    const float* c2_w   = (const float*)d_in[13];
    const float* bn2g   = (const float*)d_in[14];
    const float* bn2b   = (const float*)d_in[15];
    const float* bn2m   = (const float*)d_in[16];
    const float* bn2v   = (const float*)d_in[17];
    const float* c3_w   = (const float*)d_in[18];
    const float* bn3g   = (const float*)d_in[19];
    const float* bn3b   = (const float*)d_in[20];
    const float* bn3m   = (const float*)d_in[21];
    const float* bn3v   = (const float*)d_in[22];
    const float* c4_w   = (const float*)d_in[23];
    const float* bn4g   = (const float*)d_in[24];
    const float* bn4b   = (const float*)d_in[25];
    const float* bn4m   = (const float*)d_in[26];
    const float* bn4v   = (const float*)d_in[27];
    const float* c5_w   = (const float*)d_in[28];
    const float* bn5g   = (const float*)d_in[29];
    const float* bn5b   = (const float*)d_in[30];
    const float* bn5m   = (const float*)d_in[31];
    const float* bn5v   = (const float*)d_in[32];
    const float* proj_w = (const float*)d_in[33];
    const float* vproj_w= (const float*)d_in[34];
    const float* vproj_b= (const float*)d_in[35];
    const float* gru_wih= (const float*)d_in[36];
    const float* gru_whh= (const float*)d_in[37];
    const float* gru_bih= (const float*)d_in[38];
    const float* gru_bhh= (const float*)d_in[39];
    const float* fc_w   = (const float*)d_in[40];

    float* W = (float*)d_ws;
    size_t off = 0;
    int*   map0 = (int*)(W + off); off += 96*192;
    int*   map1 = (int*)(W + off); off += 48*96;
    float* w5t0 = W + off; off += 32*6*25;
    float* w5t1 = W + off; off += 64*32*25;
    float* wt2  = W + off; off += 64*64*9;
    float* wt3  = W + off; off += 64*64*4;
    float* wt4  = W + off; off += 128*64*9;
    float* wt5  = W + off; off += 128*128*9;
    float* bufA = W + off; off += (size_t)256*32*31*63;   // h0 / h2 / h4 / fused
    float* bufB = W + off; off += (size_t)256*64*15*31;   // h1 / h3 / h5

    // small precompute
    k_idxmap<<<72, 256, 0, stream>>>(map0, 64, 128, 64, 96*192);
    k_idxmap<<<18, 256, 0, stream>>>(map1, 31,  63, 32, 48*96);
    k_w5<<<(32*6*25 +255)/256, 256, 0, stream>>>(sc0_w, w5t0, 32, 6);
    k_w5<<<(64*32*25+255)/256, 256, 0, stream>>>(sc1_w, w5t1, 64, 32);
    k_wT<<<(64*64*9  +255)/256, 256, 0, stream>>>(c2_w, wt2, 64,  64*9);
    k_wT<<<(64*64*4  +255)/256, 256, 0, stream>>>(c3_w, wt3, 64,  64*4);
    k_wT<<<(128*64*9 +255)/256, 256, 0, stream>>>(c4_w, wt4, 128, 64*9);
    k_wT<<<(128*128*9+255)/256, 256, 0, stream>>>(c5_w, wt5, 128, 128*9);

    // backbone
    k_sconv<6,32,31,63,192,64*128,6><<<256*31, 256, 0, stream>>>(x,    map0, w5t0, bn0g,bn0b,bn0m,bn0v, bufA);
    k_sconv<32,64,15,31,96,31*63,16><<<256*15, 256, 0, stream>>>(bufA, map1, w5t1, bn1g,bn1b,bn1m,bn1v, bufB);
    // k_conv<CI,CO,KH,KW,S,IH,IW,IWP,OH,OW,CICH,CSPLIT,KTILES>
    k_conv<64,64,3,3,1,15,31,32,13,29,16,4,4><<<256*4,256,0,stream>>>(bufB, wt2, bn2g,bn2b,bn2m,bn2v, bufA);
    k_conv<64,64,2,2,2,13,29,32,6,14,16,4,1><<<256*4,256,0,stream>>>(bufA, wt3, bn3g,bn3b,bn3m,bn3v, bufB);
    k_conv<64,128,3,3,1,6,14,16,4,12,32,4,1><<<256*4,256,0,stream>>>(bufB, wt4, bn4g,bn4b,bn4m,bn4v, bufA);
    k_conv<128,128,3,3,1,4,12,12,2,10,32,2,1><<<256*2,256,0,stream>>>(bufA, wt5, bn5g,bn5b,bn5m,bn5v, bufB);

    // head
    k_head<<<256,256,0,stream>>>(bufB, vin, proj_w, vproj_w, vproj_b, bufA);
    float* outp = (float*)d_out;
    k_gru<<<256,256,0,stream>>>(bufA, hx, gru_wih, gru_whh, gru_bih, gru_bhh, outp + 1024);
    k_act<<<4,256,0,stream>>>(outp + 1024, fc_w, outp);
}

// Round 7
// 681.736 us; speedup vs baseline: 9.3346x; 1.8555x over previous
//
#include <hip/hip_runtime.h>
#include <math.h>

typedef unsigned short u16;
typedef __attribute__((ext_vector_type(8))) _Float16 half8;
typedef __attribute__((ext_vector_type(4))) float    f32x4;

#define PI_F 3.14159265358979323846f

__device__ __forceinline__ float lrelu_f(float x){ return x >= 0.f ? x : 0.05f*x; }
__device__ __forceinline__ u16 f2h(float f){ _Float16 h = (_Float16)f; u16 u; __builtin_memcpy(&u,&h,2); return u; }
__device__ __forceinline__ float h2f(u16 u){ _Float16 h; __builtin_memcpy(&h,&u,2); return (float)h; }

// ---------------------------------------------------------------------------
// Index map: xu flat index -> lat*W + lon (pure-gather form of grid_sample)
// ---------------------------------------------------------------------------
__global__ void k_idxmap(int* __restrict__ map, int H, int W, int Wo, int total)
{
    int i = blockIdx.x*blockDim.x + threadIdx.x;
    if (i >= total) return;
    int oh  = i / (Wo*9);
    int rem = i % (Wo*9);
    int ow  = rem / 9;
    int r2  = rem % 9;
    int kh  = r2/3, kw = r2%3;
    int ihc = min(oh*2, H-1);
    int lat = min(max(ihc + kh - 1, 0), H-1);
    float phi = ((float)lat + 0.5f)/(float)H * PI_F - 0.5f*PI_F;
    float ca  = fmaxf(fabsf(cosf(phi)), 1e-3f);
    float d   = fminf(0.8f/ca, 4.0f);
    float jw  = (float)((ow*2) % W);
    float lonf = rintf(jw + d*(float)(kw-1));
    int lon = (int)lonf % W; if (lon < 0) lon += W;
    map[i] = lat*W + lon;
}

// ---------------------------------------------------------------------------
// Sphere weights: fold avg_pool3(conv3x3) into 5x5/stride3, f16 [co][KP]
// (k = ci*25 + u*5 + v; zero-pad k in [K, KP))
// ---------------------------------------------------------------------------
__global__ void k_w5h(const float* __restrict__ w3, u16* __restrict__ wh,
                      int CO, int CI, int KP)
{
    int i = blockIdx.x*blockDim.x + threadIdx.x;
    if (i >= CO*KP) return;
    int k = i % KP, co = i / KP;
    float s = 0.f;
    if (k < CI*25){
        int ci = k/25, rem = k%25, u = rem/5, v = rem%5;
        const float* w = w3 + (co*CI + ci)*9;
        int p0 = max(0, u-2), p1 = min(2, u);
        int q0 = max(0, v-2), q1 = min(2, v);
        for (int p=p0;p<=p1;++p)
            for (int q=q0;q<=q1;++q) s += w[p*3+q];
        s *= (1.0f/9.0f);
    }
    wh[i] = f2h(s);
}

// plain OIHW fp32 -> f16 (flat layout already [co][k=ci*KH*KW+p*KW+q])
__global__ void k_wcvt(const float* __restrict__ w, u16* __restrict__ wh, int total)
{
    int i = blockIdx.x*blockDim.x + threadIdx.x;
    if (i < total) wh[i] = f2h(w[i]);
}

// ---------------------------------------------------------------------------
// MFMA conv engine (sphere-gather flavor). Block = (b, oh); 4 waves.
// LDS: im2col A-tile [NPAD][KCp] f16 + weight B-tile [CO][KCp] f16, K-chunked.
// Fragment layout (guide §3, m89/m92-verified): A/B lane&15 = M/N index,
// k = (lane>>4)*8 + j; D col = lane&15, row = (lane>>4)*4 + reg.
// KCp = KC + 8: keeps row pitch 16B-aligned and bank spread ~2-way (free).
// ---------------------------------------------------------------------------
template<typename IN_T,int CI,int CO,int OH,int OW,int RW,int IPLANE,
         int K,int KP,int KC,int KCp,int NT_N,int NT_CO>
__global__ __launch_bounds__(256) void k_mconv_sph(
    const IN_T* __restrict__ in, const int* __restrict__ map,
    const u16* __restrict__ wh,
    const float* __restrict__ bg, const float* __restrict__ bb,
    const float* __restrict__ bm, const float* __restrict__ bv,
    u16* __restrict__ out)
{
    constexpr int NPAD = NT_N*16;
    constexpr int TPW  = (NT_N*NT_CO)/4;
    __shared__ __align__(16) u16 sA[NPAD*KCp];
    __shared__ __align__(16) u16 sB[CO*KCp];
    int b = blockIdx.x / OH, oh = blockIdx.x % OH;
    int tid = threadIdx.x;
    const IN_T* xb = in + (size_t)b*CI*IPLANE;
    int w = tid >> 6, lane = tid & 63, l15 = lane & 15, l4 = lane >> 4;
    int nt = w % NT_N;
    f32x4 acc[TPW];
    #pragma unroll
    for (int j=0;j<TPW;++j) acc[j] = (f32x4){0.f,0.f,0.f,0.f};

    for (int kc0 = 0; kc0 < KP; kc0 += KC){
        if (kc0) __syncthreads();
        // stage A (im2col gather, f16)
        for (int i = tid; i < NPAD*KC; i += 256){
            int n = i / KC, kl = i % KC, k = kc0 + kl;
            u16 val = 0;
            if (k < K){
                int ci = k/25, rem = k%25, u = rem/5, v = rem%5;
                int r = oh*3 + u;
                int c = n*3 + v; c = c < RW-1 ? c : RW-1;
                int m = map[r*RW + c];
                if constexpr (sizeof(IN_T)==4) val = f2h(xb[(size_t)ci*IPLANE + m]);
                else                           val = xb[(size_t)ci*IPLANE + m];
            }
            sA[n*KCp + kl] = val;
        }
        // stage B (weights, contiguous 16B copies)
        for (int i = tid; i < CO*KC/8; i += 256){
            int co = i / (KC/8), j = i % (KC/8);
            uint4 v = *reinterpret_cast<const uint4*>(wh + (size_t)co*KP + kc0 + j*8);
            *reinterpret_cast<uint4*>(&sB[co*KCp + j*8]) = v;
        }
        __syncthreads();
        #pragma unroll
        for (int ks = 0; ks < KC/32; ++ks){
            half8 a = *reinterpret_cast<const half8*>(&sA[(nt*16 + l15)*KCp + ks*32 + l4*8]);
            #pragma unroll
            for (int j=0;j<TPW;++j){
                int ct = (w + j*4)/NT_N;
                half8 bf = *reinterpret_cast<const half8*>(&sB[(ct*16 + l15)*KCp + ks*32 + l4*8]);
                acc[j] = __builtin_amdgcn_mfma_f32_16x16x32_f16(a, bf, acc[j], 0, 0, 0);
            }
        }
    }
    #pragma unroll
    for (int j=0;j<TPW;++j){
        int ct = (w + j*4)/NT_N;
        int co = ct*16 + l15;
        float inv = bg[co]*rsqrtf(bv[co]+1e-5f);
        float shv = bb[co] - bm[co]*inv;
        int n0 = nt*16 + l4*4;
        size_t ob = ((size_t)(b*CO + co)*OH + oh)*OW;
        #pragma unroll
        for (int r=0;r<4;++r){
            int n = n0 + r;
            if (n < OW) out[ob + n] = f2h(lrelu_f(fmaf(acc[j][r], inv, shv)));
        }
    }
}

// ---------------------------------------------------------------------------
// MFMA conv engine (direct VALID-conv flavor). KP == K (all layers 32-divisible).
// ---------------------------------------------------------------------------
template<int CI,int CO,int KH,int KW,int S,int IH,int IW,int OH,int OW,
         int K,int KC,int KCp,int NT_N,int NT_CO>
__global__ __launch_bounds__(256) void k_mconv_dir(
    const u16* __restrict__ in, const u16* __restrict__ wh,
    const float* __restrict__ bg, const float* __restrict__ bb,
    const float* __restrict__ bm, const float* __restrict__ bv,
    u16* __restrict__ out)
{
    constexpr int NPAD = NT_N*16;
    constexpr int TPW  = (NT_N*NT_CO)/4;
    constexpr int KPQ  = KH*KW;
    __shared__ __align__(16) u16 sA[NPAD*KCp];
    __shared__ __align__(16) u16 sB[CO*KCp];
    int b = blockIdx.x / OH, oh = blockIdx.x % OH;
    int tid = threadIdx.x;
    int w = tid >> 6, lane = tid & 63, l15 = lane & 15, l4 = lane >> 4;
    int nt = w % NT_N;
    f32x4 acc[TPW];
    #pragma unroll
    for (int j=0;j<TPW;++j) acc[j] = (f32x4){0.f,0.f,0.f,0.f};

    for (int kc0 = 0; kc0 < K; kc0 += KC){
        if (kc0) __syncthreads();
        for (int i = tid; i < NPAD*KC; i += 256){
            int n = i / KC, kl = i % KC, k = kc0 + kl;
            int ci = k/KPQ, rem = k%KPQ, p = rem/KW, q = rem%KW;
            int row = oh*S + p;
            int col = n*S + q; col = col < IW-1 ? col : IW-1;
            sA[n*KCp + kl] = in[((size_t)(b*CI + ci)*IH + row)*IW + col];
        }
        for (int i = tid; i < CO*KC/8; i += 256){
            int co = i / (KC/8), j = i % (KC/8);
            uint4 v = *reinterpret_cast<const uint4*>(wh + (size_t)co*K + kc0 + j*8);
            *reinterpret_cast<uint4*>(&sB[co*KCp + j*8]) = v;
        }
        __syncthreads();
        #pragma unroll
        for (int ks = 0; ks < KC/32; ++ks){
            half8 a = *reinterpret_cast<const half8*>(&sA[(nt*16 + l15)*KCp + ks*32 + l4*8]);
            #pragma unroll
            for (int j=0;j<TPW;++j){
                int ct = (w + j*4)/NT_N;
                half8 bf = *reinterpret_cast<const half8*>(&sB[(ct*16 + l15)*KCp + ks*32 + l4*8]);
                acc[j] = __builtin_amdgcn_mfma_f32_16x16x32_f16(a, bf, acc[j], 0, 0, 0);
            }
        }
    }
    #pragma unroll
    for (int j=0;j<TPW;++j){
        int ct = (w + j*4)/NT_N;
        int co = ct*16 + l15;
        float inv = bg[co]*rsqrtf(bv[co]+1e-5f);
        float shv = bb[co] - bm[co]*inv;
        int n0 = nt*16 + l4*4;
        size_t ob = ((size_t)(b*CO + co)*OH + oh)*OW;
        #pragma unroll
        for (int r=0;r<4;++r){
            int n = n0 + r;
            if (n < OW) out[ob + n] = f2h(lrelu_f(fmaf(acc[j][r], inv, shv)));
        }
    }
}

// ---------------------------------------------------------------------------
// fused = lrelu(h5_flat @ proj_w.T + v @ vproj_w.T + vproj_b)   (h5 is f16)
// ---------------------------------------------------------------------------
__global__ __launch_bounds__(256) void k_head(
    const u16* __restrict__ h5, const float* __restrict__ vin,
    const float* __restrict__ proj_w, const float* __restrict__ vproj_w,
    const float* __restrict__ vproj_b, float* __restrict__ fused)
{
    __shared__ __align__(16) float sh[2560];
    __shared__ float sv[9];
    int b = blockIdx.x, tid = threadIdx.x;
    for (int i = tid; i < 2560; i += 256) sh[i] = h2f(h5[(size_t)b*2560 + i]);
    if (tid < 9) sv[tid] = vin[b*9 + tid];
    __syncthreads();
    const float* pw = proj_w + (size_t)tid*2560;
    float acc = 0.f;
    for (int k=0;k<2560;k+=4){
        float4 s4 = *reinterpret_cast<const float4*>(sh+k);
        float4 w4 = *reinterpret_cast<const float4*>(pw+k);
        acc = fmaf(s4.x,w4.x, fmaf(s4.y,w4.y, fmaf(s4.z,w4.z, fmaf(s4.w,w4.w, acc))));
    }
    float av = 0.f;
    #pragma unroll
    for (int k=0;k<9;++k) av += sv[k]*vproj_w[tid*9+k];
    fused[b*256+tid] = lrelu_f(acc + av + vproj_b[tid]);
}

// ---------------------------------------------------------------------------
// GRU cell
// ---------------------------------------------------------------------------
__global__ __launch_bounds__(256) void k_gru(
    const float* __restrict__ fused, const float* __restrict__ hx,
    const float* __restrict__ wih, const float* __restrict__ whh,
    const float* __restrict__ bih, const float* __restrict__ bhh,
    float* __restrict__ hx_new)
{
    __shared__ __align__(16) float sf[256];
    __shared__ __align__(16) float shx[256];
    int b = blockIdx.x, j = threadIdx.x;
    sf[j]  = fused[b*256+j];
    shx[j] = hx[b*256+j];
    __syncthreads();
    float ga[3], gb[3];
    #pragma unroll
    for (int gi=0; gi<3; ++gi){
        const float* wi = wih + ((size_t)gi*256 + j)*256;
        const float* wh = whh + ((size_t)gi*256 + j)*256;
        float a = 0.f, c = 0.f;
        for (int k=0;k<256;k+=4){
            float4 f4  = *reinterpret_cast<const float4*>(sf+k);
            float4 h4  = *reinterpret_cast<const float4*>(shx+k);
            float4 wi4 = *reinterpret_cast<const float4*>(wi+k);
            float4 wh4 = *reinterpret_cast<const float4*>(wh+k);
            a = fmaf(f4.x,wi4.x, fmaf(f4.y,wi4.y, fmaf(f4.z,wi4.z, fmaf(f4.w,wi4.w, a))));
            c = fmaf(h4.x,wh4.x, fmaf(h4.y,wh4.y, fmaf(h4.z,wh4.z, fmaf(h4.w,wh4.w, c))));
        }
        ga[gi] = a + bih[gi*256+j];
        gb[gi] = c + bhh[gi*256+j];
    }
    float r = 1.f/(1.f+expf(-(ga[0]+gb[0])));
    float z = 1.f/(1.f+expf(-(ga[1]+gb[1])));
    float n = tanhf(ga[2] + r*gb[2]);
    hx_new[b*256+j] = (1.f-z)*n + z*shx[j];
}

// act = lrelu(hx_new) @ fc_w.T
__global__ void k_act(const float* __restrict__ hx_new, const float* __restrict__ fc_w,
                      float* __restrict__ act)
{
    int t = blockIdx.x*blockDim.x + threadIdx.x;
    if (t >= 1024) return;
    int b = t >> 2, o = t & 3;
    const float* h = hx_new + b*256;
    const float* w = fc_w + o*256;
    float acc = 0.f;
    for (int k=0;k<256;++k) acc = fmaf(lrelu_f(h[k]), w[k], acc);
    act[t] = acc;
}

extern "C" void kernel_launch(void* const* d_in, const int* in_sizes, int n_in,
                              void* d_out, int out_size, void* d_ws, size_t ws_size,
                              hipStream_t stream)
{
    const float* x      = (const float*)d_in[0];
    const float* vin    = (const float*)d_in[1];
    const float* hx     = (const float*)d_in[2];
    const float* sc0_w  = (const float*)d_in[3];
    const float* bn0g   = (const float*)d_in[4];
    const float* bn0b   = (const float*)d_in[5];
    const float* bn0m   = (const float*)d_in[6];
    const float* bn0v   = (const float*)d_in[7];
    const float* sc1_w  = (const float*)d_in[8];
    const float* bn1g   = (const float*)d_in[9];
    const float* bn1b   = (const float*)d_in[10];
    const float* bn1m   = (const float*)d_in[11];
    const float* bn1v   = (const float*)d_in[12];
    const float* c2_w   = (const float*)d_in[13];
    const float* bn2g   = (const float*)d_in[14];
    const float* bn2b   = (const float*)d_in[15];
    const float* bn2m   = (const float*)d_in[16];
    const float* bn2v   = (const float*)d_in[17];
    const float* c3_w   = (const float*)d_in[18];
    const float* bn3g   = (const float*)d_in[19];
    const float* bn3b   = (const float*)d_in[20];
    const float* bn3m   = (const float*)d_in[21];
    const float* bn3v   = (const float*)d_in[22];
    const float* c4_w   = (const float*)d_in[23];
    const float* bn4g   = (const float*)d_in[24];
    const float* bn4b   = (const float*)d_in[25];
    const float* bn4m   = (const float*)d_in[26];
    const float* bn4v   = (const float*)d_in[27];
    const float* c5_w   = (const float*)d_in[28];
    const float* bn5g   = (const float*)d_in[29];
    const float* bn5b   = (const float*)d_in[30];
    const float* bn5m   = (const float*)d_in[31];
    const float* bn5v   = (const float*)d_in[32];
    const float* proj_w = (const float*)d_in[33];
    const float* vproj_w= (const float*)d_in[34];
    const float* vproj_b= (const float*)d_in[35];
    const float* gru_wih= (const float*)d_in[36];
    const float* gru_whh= (const float*)d_in[37];
    const float* gru_bih= (const float*)d_in[38];
    const float* gru_bhh= (const float*)d_in[39];
    const float* fc_w   = (const float*)d_in[40];

    char* base = (char*)d_ws;
    size_t off = 0;
    auto alloc = [&](size_t bytes)->char*{
        char* p = base + off; off += (bytes + 255) & ~(size_t)255; return p;
    };
    int* map0 = (int*)alloc(96*192*4);
    int* map1 = (int*)alloc(48*96*4);
    u16* wb0  = (u16*)alloc(32*160*2);
    u16* wb1  = (u16*)alloc(64*800*2);
    u16* wb2  = (u16*)alloc((size_t)64*576*2);
    u16* wb3  = (u16*)alloc((size_t)64*256*2);
    u16* wb4  = (u16*)alloc((size_t)128*576*2);
    u16* wb5  = (u16*)alloc((size_t)128*1152*2);
    u16* h0   = (u16*)alloc((size_t)256*32*1953*2);
    u16* h1   = (u16*)alloc((size_t)256*64*465*2);
    u16* h2   = (u16*)alloc((size_t)256*64*377*2);
    u16* h3   = (u16*)alloc((size_t)256*64*84*2);
    u16* h4   = (u16*)alloc((size_t)256*128*48*2);
    u16* h5   = (u16*)alloc((size_t)256*128*20*2);
    float* fused = (float*)alloc((size_t)65536*4);

    // precompute: index maps + f16 weights
    k_idxmap<<<72, 256, 0, stream>>>(map0, 64, 128, 64, 96*192);
    k_idxmap<<<18, 256, 0, stream>>>(map1, 31,  63, 32, 48*96);
    k_w5h<<<(32*160 +255)/256, 256, 0, stream>>>(sc0_w, wb0, 32, 6, 160);
    k_w5h<<<(64*800 +255)/256, 256, 0, stream>>>(sc1_w, wb1, 64, 32, 800);
    k_wcvt<<<(36864 +255)/256, 256, 0, stream>>>(c2_w, wb2, 36864);
    k_wcvt<<<(16384 +255)/256, 256, 0, stream>>>(c3_w, wb3, 16384);
    k_wcvt<<<(73728 +255)/256, 256, 0, stream>>>(c4_w, wb4, 73728);
    k_wcvt<<<(147456+255)/256, 256, 0, stream>>>(c5_w, wb5, 147456);

    // backbone (MFMA f16)
    // k_mconv_sph<IN_T,CI,CO,OH,OW,RW,IPLANE,K,KP,KC,KCp,NT_N,NT_CO>
    k_mconv_sph<float,6,32,31,63,192,8192,150,160,160,168,4,2>
        <<<256*31, 256, 0, stream>>>(x,  map0, wb0, bn0g,bn0b,bn0m,bn0v, h0);
    k_mconv_sph<u16,32,64,15,31,96,1953,800,800,160,168,2,4>
        <<<256*15, 256, 0, stream>>>(h0, map1, wb1, bn1g,bn1b,bn1m,bn1v, h1);
    // k_mconv_dir<CI,CO,KH,KW,S,IH,IW,OH,OW,K,KC,KCp,NT_N,NT_CO>
    k_mconv_dir<64,64,3,3,1,15,31,13,29,576,192,200,2,4>
        <<<256*13, 256, 0, stream>>>(h1, wb2, bn2g,bn2b,bn2m,bn2v, h2);
    k_mconv_dir<64,64,2,2,2,13,29,6,14,256,128,136,1,4>
        <<<256*6,  256, 0, stream>>>(h2, wb3, bn3g,bn3b,bn3m,bn3v, h3);
    k_mconv_dir<64,128,3,3,1,6,14,4,12,576,96,104,1,8>
        <<<256*4,  256, 0, stream>>>(h3, wb4, bn4g,bn4b,bn4m,bn4v, h4);
    k_mconv_dir<128,128,3,3,1,4,12,2,10,1152,96,104,1,8>
        <<<256*2,  256, 0, stream>>>(h4, wb5, bn5g,bn5b,bn5m,bn5v, h5);

    // head
    k_head<<<256, 256, 0, stream>>>(h5, vin, proj_w, vproj_w, vproj_b, fused);
    float* outp = (float*)d_out;
    k_gru<<<256, 256, 0, stream>>>(fused, hx, gru_wih, gru_whh, gru_bih, gru_bhh, outp + 1024);
    k_act<<<4, 256, 0, stream>>>(outp + 1024, fc_w, outp);
}